// Round 15
// baseline (2368.012 us; speedup 1.0000x reference)
//
#include <hip/hip_runtime.h>
#include <math.h>

#define TPB 64
#define NPT 270000
#define SOFTB 20.0f
#define CVGT 1e-5f
#define DVGT 1.0f
#define EPSB 1e-6f

// ws float offsets
#define WS_TINV 0      // 9*16 = 144 floats
#define WS_W0T  256    // 64*4 floats: cols 0..2 = W0 row k, col 3 = b0[k]

typedef __attribute__((ext_vector_type(2))) float f2;

__device__ __forceinline__ f2 pk_fma(f2 a, f2 b, f2 c) {
#if __has_builtin(__builtin_elementwise_fma)
    return __builtin_elementwise_fma(a, b, c);
#else
    f2 r; r.x = fmaf(a.x, b.x, c.x); r.y = fmaf(a.y, b.y, c.y); return r;
#endif
}

__global__ void prep_kernel(const float* __restrict__ tfs,
                            const float* __restrict__ W0, const float* __restrict__ b0,
                            float* __restrict__ ws) {
    int t = threadIdx.x;   // 256 threads, 1 block
    if (t < 9) {
        const int bones[9] = {0, 1, 2, 4, 5, 16, 17, 18, 19};
        const float* T = tfs + bones[t] * 16;
        float r00=T[0], r01=T[1], r02=T[2],  t0=T[3];
        float r10=T[4], r11=T[5], r12=T[6],  t1=T[7];
        float r20=T[8], r21=T[9], r22=T[10], t2=T[11];
        float c00 = r11*r22 - r12*r21;
        float c01 = r12*r20 - r10*r22;
        float c02 = r10*r21 - r11*r20;
        float det = r00*c00 + r01*c01 + r02*c02;
        float id  = 1.0f / det;
        float i00=c00*id, i01=(r02*r21-r01*r22)*id, i02=(r01*r12-r02*r11)*id;
        float i10=c01*id, i11=(r00*r22-r02*r20)*id, i12=(r02*r10-r00*r12)*id;
        float i20=c02*id, i21=(r01*r20-r00*r21)*id, i22=(r00*r11-r01*r10)*id;
        float* O = ws + WS_TINV + t * 16;
        O[0]=i00; O[1]=i01; O[2]=i02;  O[3]=-(i00*t0+i01*t1+i02*t2);
        O[4]=i10; O[5]=i11; O[6]=i12;  O[7]=-(i10*t0+i11*t1+i12*t2);
        O[8]=i20; O[9]=i21; O[10]=i22; O[11]=-(i20*t0+i21*t1+i22*t2);
        O[12]=0.f; O[13]=0.f; O[14]=0.f; O[15]=1.f;
    }
    for (int i = t; i < 64*4; i += 256) {
        int k = i >> 2, cidx = i & 3;
        ws[WS_W0T + i] = (cidx < 3) ? W0[cidx*64 + k] : b0[k];
    }
}

__global__ __launch_bounds__(TPB) void deform_kernel(
    const float* __restrict__ xd,
    const float* __restrict__ tfs,
    const float* __restrict__ W1, const float* __restrict__ b1,
    const float* __restrict__ W2, const float* __restrict__ b2,
    const float* __restrict__ ws,
    float* __restrict__ out)
{
    // PAIR MODE: lanes 2i, 2i+1 process the SAME point; lane half h owns
    // hidden units [h*32, h*32+32). Cross-lane sums via __shfl_xor(.,1):
    // own+other is commutative -> both lanes get bit-identical values ->
    // pairs stay in lockstep (no intra-pair divergence, ever).
    //
    // Per-thread LDS columns (lanes stride-1 -> conflict-free):
    //   init/Jacobian: slots 0..23 = w ; Broyden: 0..8 Ji, 9 gno, 10..12 dx, 13..15 tx
    __shared__ float stash[24 * TPB];

    const int tid = threadIdx.x;
    const int gt  = blockIdx.x * TPB + tid;
    const int p    = gt >> 1;
    const int half = gt & 1;
    const bool live = (p < NPT);
    const int pc = live ? p : 0;
    const int n  = pc / 9;
    const int c  = pc - n * 9;

    float tx0 = xd[n*3+0], tx1 = xd[n*3+1], tx2 = xd[n*3+2];

    const float* Ti  = ws + WS_TINV + c * 16;
    const float* W0T = ws + WS_W0T;

    float x0 = fmaf(Ti[0], tx0, fmaf(Ti[1], tx1, fmaf(Ti[2],  tx2, Ti[3])));
    float x1 = fmaf(Ti[4], tx0, fmaf(Ti[5], tx1, fmaf(Ti[6],  tx2, Ti[7])));
    float x2 = fmaf(Ti[8], tx0, fmaf(Ti[9], tx1, fmaf(Ti[10], tx2, Ti[11])));

    f2 wr[12];   // layer-3 accumulators -> softmax weights (static-indexed only)

    // forward: lane computes z1 for its OWN 32 hidden units (16 f2), folds its
    // half into wr, then one shfl-exchange rebuilds the full wr on both lanes.
    auto forward = [&](float a0, float a1, float a2, float& o0, float& o1, float& o2) {
        const f2* b2v = (const f2*)b2;
        #pragma unroll
        for (int q = 0; q < 12; ++q) wr[q] = half ? (f2)0.f : b2v[q];
        f2 z1[16];
        const f2* b1v = (const f2*)(b1 + half*32);
        #pragma unroll
        for (int j = 0; j < 16; ++j) z1[j] = b1v[j];
        #pragma unroll 2
        for (int k = 0; k < 64; ++k) {
            float w0a = W0T[k*4+0], w0b = W0T[k*4+1], w0c = W0T[k*4+2], w0d = W0T[k*4+3];
            float z  = fmaf(a0, w0a, fmaf(a1, w0b, fmaf(a2, w0c, w0d)));
            float hk = fmaxf(z, 0.f) + __logf(1.f + __expf(-fabsf(z)));
            f2 hk2 = hk;   // broadcast
            const f2* Wr2 = (const f2*)(W1 + k*64 + half*32);
            #pragma unroll
            for (int j = 0; j < 16; ++j) z1[j] = pk_fma(hk2, Wr2[j], z1[j]);
        }
        #pragma unroll
        for (int j = 0; j < 16; ++j) {
            float za = z1[j].x, zb = z1[j].y;
            float ha = fmaxf(za, 0.f) + __logf(1.f + __expf(-fabsf(za)));
            float hb = fmaxf(zb, 0.f) + __logf(1.f + __expf(-fabsf(zb)));
            const f2* Wa = (const f2*)(W2 + (half*32 + 2*j  )*24);
            const f2* Wb = (const f2*)(W2 + (half*32 + 2*j+1)*24);
            f2 ha2 = ha, hb2 = hb;
            #pragma unroll
            for (int q = 0; q < 12; ++q) wr[q] = pk_fma(ha2, Wa[q], wr[q]);
            #pragma unroll
            for (int q = 0; q < 12; ++q) wr[q] = pk_fma(hb2, Wb[q], wr[q]);
        }
        // exchange: full wr = own half + partner half (commutative -> identical)
        #pragma unroll
        for (int q = 0; q < 12; ++q) {
            f2 o;
            o.x = __shfl_xor(wr[q].x, 1, 64);
            o.y = __shfl_xor(wr[q].y, 1, 64);
            wr[q] += o;
        }
        // softmax(SOFTB * m) — pairwise tree max (both lanes, identical)
        f2 m0 = __builtin_elementwise_max(wr[0], wr[1]);
        f2 m1 = __builtin_elementwise_max(wr[2], wr[3]);
        f2 m2 = __builtin_elementwise_max(wr[4], wr[5]);
        f2 m3 = __builtin_elementwise_max(wr[6], wr[7]);
        f2 m4 = __builtin_elementwise_max(wr[8], wr[9]);
        f2 m5 = __builtin_elementwise_max(wr[10], wr[11]);
        m0 = __builtin_elementwise_max(m0, m1);
        m2 = __builtin_elementwise_max(m2, m3);
        m4 = __builtin_elementwise_max(m4, m5);
        m0 = __builtin_elementwise_max(m0, m2);
        m0 = __builtin_elementwise_max(m0, m4);
        float mx = fmaxf(m0.x, m0.y);
        float ssum = 0.f;
        #pragma unroll
        for (int q = 0; q < 12; ++q) {
            float ea = __expf(SOFTB*(wr[q].x - mx));
            float eb = __expf(SOFTB*(wr[q].y - mx));
            wr[q].x = ea; wr[q].y = eb;
            ssum += ea; ssum += eb;
        }
        float inv = 1.0f / ssum;
        o0 = 0.f; o1 = 0.f; o2 = 0.f;
        #pragma unroll
        for (int q = 0; q < 24; ++q) {
            float wq = ((q & 1) ? wr[q>>1].y : wr[q>>1].x) * inv;
            if (q & 1) wr[q>>1].y = wq; else wr[q>>1].x = wq;
            const float* Tn = tfs + q*16;
            float y0 = fmaf(Tn[0], a0, fmaf(Tn[1], a1, fmaf(Tn[2],  a2, Tn[3])));
            float y1 = fmaf(Tn[4], a0, fmaf(Tn[5], a1, fmaf(Tn[6],  a2, Tn[7])));
            float y2 = fmaf(Tn[8], a0, fmaf(Tn[9], a1, fmaf(Tn[10], a2, Tn[11])));
            o0 = fmaf(wq, y0, o0); o1 = fmaf(wq, y1, o1); o2 = fmaf(wq, y2, o2);
        }
    };

    // ---- init forward (leaves full w in wr) ----
    float f0, f1, f2s;
    forward(x0, x1, x2, f0, f1, f2s);

    // persist w to LDS for the Jacobian
    #pragma unroll
    for (int q = 0; q < 24; ++q)
        stash[q*TPB + tid] = (q & 1) ? wr[q>>1].y : wr[q>>1].x;

    // ---- Jacobian: 3 tangents × 2 local 16-unit chunks per lane ----
    // Lane covers its own 32 hidden units; dmc exchanged per chunk.
    float Jm[9];   // runtime-t indexed -> scratch; cold
    #pragma unroll 1
    for (int t = 0; t < 3; ++t) {
        float dot = 0.f, sA = 0.f, sB = 0.f, sC = 0.f;
        #pragma unroll 1
        for (int cc = 0; cc < 2; ++cc) {
            f2 z1c[8], d1c[8];
            const f2* b1c = (const f2*)(b1 + half*32 + cc*16);
            #pragma unroll
            for (int j = 0; j < 8; ++j) { z1c[j] = b1c[j]; d1c[j] = (f2)0.f; }
            #pragma unroll 2
            for (int k = 0; k < 64; ++k) {
                float w0a = W0T[k*4+0], w0b = W0T[k*4+1], w0c = W0T[k*4+2], w0d = W0T[k*4+3];
                float wt  = W0T[k*4 + t];
                float z  = fmaf(x0, w0a, fmaf(x1, w0b, fmaf(x2, w0c, w0d)));
                float e  = __expf(-z);
                float hk = z + __logf(1.f + e);          // softplus(z) (shared e)
                float sg = 1.0f / (1.0f + e);            // sigma(z)
                float dh0 = sg * wt;
                f2 hk2 = hk, dh02 = dh0;
                const f2* Wr2 = (const f2*)(W1 + k*64 + half*32 + cc*16);
                #pragma unroll
                for (int j = 0; j < 8; ++j) {
                    z1c[j] = pk_fma(hk2,  Wr2[j], z1c[j]);
                    d1c[j] = pk_fma(dh02, Wr2[j], d1c[j]);
                }
            }
            f2 dmc[12];
            #pragma unroll
            for (int q = 0; q < 12; ++q) dmc[q] = (f2)0.f;
            #pragma unroll
            for (int j = 0; j < 16; ++j) {
                float zz = (j & 1) ? z1c[j>>1].y : z1c[j>>1].x;
                float dd = (j & 1) ? d1c[j>>1].y : d1c[j>>1].x;
                float sg1 = 1.0f / (1.0f + __expf(-zz));   // sigma(z1)
                float dh1 = dd * sg1;
                f2 dh12 = dh1;
                const f2* W2r = (const f2*)(W2 + (half*32 + cc*16 + j)*24);
                #pragma unroll
                for (int q = 0; q < 12; ++q) dmc[q] = pk_fma(dh12, W2r[q], dmc[q]);
            }
            // exchange: combined-chunk dm (own + partner), identical on both lanes
            #pragma unroll
            for (int q = 0; q < 12; ++q) {
                f2 o;
                o.x = __shfl_xor(dmc[q].x, 1, 64);
                o.y = __shfl_xor(dmc[q].y, 1, 64);
                dmc[q] += o;
            }
            // fold (both lanes, identical)
            #pragma unroll
            for (int q = 0; q < 24; ++q) {
                float dmq = (q & 1) ? dmc[q>>1].y : dmc[q>>1].x;
                float wd = stash[q*TPB + tid] * dmq;           // w from LDS
                dot += wd;
                const float* Tn = tfs + q*16;
                float y0 = fmaf(Tn[0], x0, fmaf(Tn[1], x1, fmaf(Tn[2],  x2, Tn[3])));
                float y1 = fmaf(Tn[4], x0, fmaf(Tn[5], x1, fmaf(Tn[6],  x2, Tn[7])));
                float y2 = fmaf(Tn[8], x0, fmaf(Tn[9], x1, fmaf(Tn[10], x2, Tn[11])));
                sA = fmaf(wd, y0, sA); sB = fmaf(wd, y1, sB); sC = fmaf(wd, y2, sC);
            }
        }
        float ab0 = 0.f, ab1 = 0.f, ab2 = 0.f;
        #pragma unroll
        for (int q = 0; q < 24; ++q) {
            float wq = stash[q*TPB + tid];                     // w from LDS
            const float* Tn = tfs + q*16;
            ab0 = fmaf(wq, Tn[0 + t], ab0);
            ab1 = fmaf(wq, Tn[4 + t], ab1);
            ab2 = fmaf(wq, Tn[8 + t], ab2);
        }
        Jm[0 + t] = ab0 + SOFTB*(sA - dot*f0);
        Jm[3 + t] = ab1 + SOFTB*(sB - dot*f1);
        Jm[6 + t] = ab2 + SOFTB*(sC - dot*f2s);
    }

    // J_inv_init = inv(J) (adjugate) -> Ji into LDS (w slots now dead)
    {
        float m00=Jm[0], m01=Jm[1], m02=Jm[2];
        float m10=Jm[3], m11=Jm[4], m12=Jm[5];
        float m20=Jm[6], m21=Jm[7], m22=Jm[8];
        float c00 = m11*m22 - m12*m21, c01 = m12*m20 - m10*m22, c02 = m10*m21 - m11*m20;
        float det = m00*c00 + m01*c01 + m02*c02;
        float idet = 1.0f / det;
        stash[ 0*TPB+tid] = c00*idet;
        stash[ 1*TPB+tid] = (m02*m21-m01*m22)*idet;
        stash[ 2*TPB+tid] = (m01*m12-m02*m11)*idet;
        stash[ 3*TPB+tid] = c01*idet;
        stash[ 4*TPB+tid] = (m00*m22-m02*m20)*idet;
        stash[ 5*TPB+tid] = (m02*m10-m00*m12)*idet;
        stash[ 6*TPB+tid] = c02*idet;
        stash[ 7*TPB+tid] = (m01*m20-m00*m21)*idet;
        stash[ 8*TPB+tid] = (m00*m11-m01*m10)*idet;
    }
    // tx -> LDS (dead in registers afterwards)
    stash[13*TPB+tid] = tx0;
    stash[14*TPB+tid] = tx1;
    stash[15*TPB+tid] = tx2;

    // ---- Broyden (Ji/gno/dx/tx live in LDS across each forward) ----
    float g0 = f0 - tx0, g1 = f1 - tx1, g2 = f2s - tx2;
    float u0, u1, u2;
    {
        float Ji0=stash[0*TPB+tid], Ji1=stash[1*TPB+tid], Ji2=stash[2*TPB+tid];
        float Ji3=stash[3*TPB+tid], Ji4=stash[4*TPB+tid], Ji5=stash[5*TPB+tid];
        float Ji6=stash[6*TPB+tid], Ji7=stash[7*TPB+tid], Ji8=stash[8*TPB+tid];
        stash[9*TPB+tid] = sqrtf(g0*g0 + g1*g1 + g2*g2);   // gno
        u0 = -(Ji0*g0 + Ji1*g1 + Ji2*g2);
        u1 = -(Ji3*g0 + Ji4*g1 + Ji5*g2);
        u2 = -(Ji6*g0 + Ji7*g1 + Ji8*g2);
    }
    bool valid = true;

    for (int it = 0; it < 20; ++it) {
        if (!__any((int)valid)) break;
        if (valid) {
            // dx -> stash; x += dx
            stash[10*TPB+tid] = u0;
            stash[11*TPB+tid] = u1;
            stash[12*TPB+tid] = u2;
            x0 += u0; x1 += u1; x2 += u2;
            float fn0, fn1, fn2;
            forward(x0, x1, x2, fn0, fn1, fn2);
            float ng0 = fn0 - stash[13*TPB+tid];
            float ng1 = fn1 - stash[14*TPB+tid];
            float ng2 = fn2 - stash[15*TPB+tid];
            float dg0 = ng0 - g0, dg1 = ng1 - g1, dg2 = ng2 - g2;
            g0 = ng0; g1 = ng1; g2 = ng2;
            float gn  = sqrtf(g0*g0 + g1*g1 + g2*g2);
            float gno = fminf(gn, stash[9*TPB+tid]);   // NaN keeps old (matches where)
            stash[9*TPB+tid] = gno;
            valid = (gno > CVGT) && (gn < DVGT);       // NaN -> false (matches)
            if (valid) {
                float Ji0=stash[0*TPB+tid], Ji1=stash[1*TPB+tid], Ji2=stash[2*TPB+tid];
                float Ji3=stash[3*TPB+tid], Ji4=stash[4*TPB+tid], Ji5=stash[5*TPB+tid];
                float Ji6=stash[6*TPB+tid], Ji7=stash[7*TPB+tid], Ji8=stash[8*TPB+tid];
                float dx0=stash[10*TPB+tid], dx1=stash[11*TPB+tid], dx2=stash[12*TPB+tid];
                float v0 = dx0*Ji0 + dx1*Ji3 + dx2*Ji6;
                float v1 = dx0*Ji1 + dx1*Ji4 + dx2*Ji7;
                float v2 = dx0*Ji2 + dx1*Ji5 + dx2*Ji8;
                float a0 = dx0 - (Ji0*dg0 + Ji1*dg1 + Ji2*dg2);
                float a1 = dx1 - (Ji3*dg0 + Ji4*dg1 + Ji5*dg2);
                float a2 = dx2 - (Ji6*dg0 + Ji7*dg1 + Ji8*dg2);
                float b = v0*dg0 + v1*dg1 + v2*dg2;
                b += (b >= 0.f) ? EPSB : -EPSB;
                float ib = 1.0f / b;
                a0 *= ib; a1 *= ib; a2 *= ib;
                Ji0 = fmaf(a0, v0, Ji0); Ji1 = fmaf(a0, v1, Ji1); Ji2 = fmaf(a0, v2, Ji2);
                Ji3 = fmaf(a1, v0, Ji3); Ji4 = fmaf(a1, v1, Ji4); Ji5 = fmaf(a1, v2, Ji5);
                Ji6 = fmaf(a2, v0, Ji6); Ji7 = fmaf(a2, v1, Ji7); Ji8 = fmaf(a2, v2, Ji8);
                stash[0*TPB+tid]=Ji0; stash[1*TPB+tid]=Ji1; stash[2*TPB+tid]=Ji2;
                stash[3*TPB+tid]=Ji3; stash[4*TPB+tid]=Ji4; stash[5*TPB+tid]=Ji5;
                stash[6*TPB+tid]=Ji6; stash[7*TPB+tid]=Ji7; stash[8*TPB+tid]=Ji8;
                u0 = -(Ji0*g0 + Ji1*g1 + Ji2*g2);
                u1 = -(Ji3*g0 + Ji4*g1 + Ji5*g2);
                u2 = -(Ji6*g0 + Ji7*g1 + Ji8*g2);
            }
        }
    }

    if (live && half == 0) {
        out[p*3+0] = x0;
        out[p*3+1] = x1;
        out[p*3+2] = x2;
    }
}

extern "C" void kernel_launch(void* const* d_in, const int* in_sizes, int n_in,
                              void* d_out, int out_size, void* d_ws, size_t ws_size,
                              hipStream_t stream) {
    const float* xd  = (const float*)d_in[0];
    const float* tfs = (const float*)d_in[1];
    const float* W0  = (const float*)d_in[2];
    const float* b0  = (const float*)d_in[3];
    const float* W1  = (const float*)d_in[4];
    const float* b1  = (const float*)d_in[5];
    const float* W2  = (const float*)d_in[6];
    const float* b2  = (const float*)d_in[7];
    float* out = (float*)d_out;
    float* ws  = (float*)d_ws;

    prep_kernel<<<1, 256, 0, stream>>>(tfs, W0, b0, ws);
    int nblk = (2*NPT + TPB - 1) / TPB;
    deform_kernel<<<nblk, TPB, 0, stream>>>(xd, tfs, W1, b1, W2, b2, ws, out);
}

// Round 16
// 743.098 us; speedup vs baseline: 3.1867x; 3.1867x over previous
//
#include <hip/hip_runtime.h>
#include <math.h>

#define TPB 64
#define NPT 270000
#define SOFTB 20.0f
#define CVGT 1e-5f
#define DVGT 1.0f
#define EPSB 1e-6f

// ws float offsets
#define WS_TINV 0      // 9*16 = 144 floats
#define WS_W0T  256    // 64*4 floats: cols 0..2 = W0 row k, col 3 = b0[k]

typedef __attribute__((ext_vector_type(2))) float f2;

__device__ __forceinline__ f2 pk_fma(f2 a, f2 b, f2 c) {
#if __has_builtin(__builtin_elementwise_fma)
    return __builtin_elementwise_fma(a, b, c);
#else
    f2 r; r.x = fmaf(a.x, b.x, c.x); r.y = fmaf(a.y, b.y, c.y); return r;
#endif
}

__global__ void prep_kernel(const float* __restrict__ tfs,
                            const float* __restrict__ W0, const float* __restrict__ b0,
                            float* __restrict__ ws) {
    int t = threadIdx.x;   // 256 threads, 1 block
    if (t < 9) {
        const int bones[9] = {0, 1, 2, 4, 5, 16, 17, 18, 19};
        const float* T = tfs + bones[t] * 16;
        float r00=T[0], r01=T[1], r02=T[2],  t0=T[3];
        float r10=T[4], r11=T[5], r12=T[6],  t1=T[7];
        float r20=T[8], r21=T[9], r22=T[10], t2=T[11];
        float c00 = r11*r22 - r12*r21;
        float c01 = r12*r20 - r10*r22;
        float c02 = r10*r21 - r11*r20;
        float det = r00*c00 + r01*c01 + r02*c02;
        float id  = 1.0f / det;
        float i00=c00*id, i01=(r02*r21-r01*r22)*id, i02=(r01*r12-r02*r11)*id;
        float i10=c01*id, i11=(r00*r22-r02*r20)*id, i12=(r02*r10-r00*r12)*id;
        float i20=c02*id, i21=(r01*r20-r00*r21)*id, i22=(r00*r11-r01*r10)*id;
        float* O = ws + WS_TINV + t * 16;
        O[0]=i00; O[1]=i01; O[2]=i02;  O[3]=-(i00*t0+i01*t1+i02*t2);
        O[4]=i10; O[5]=i11; O[6]=i12;  O[7]=-(i10*t0+i11*t1+i12*t2);
        O[8]=i20; O[9]=i21; O[10]=i22; O[11]=-(i20*t0+i21*t1+i22*t2);
        O[12]=0.f; O[13]=0.f; O[14]=0.f; O[15]=1.f;
    }
    for (int i = t; i < 64*4; i += 256) {
        int k = i >> 2, cidx = i & 3;
        ws[WS_W0T + i] = (cidx < 3) ? W0[cidx*64 + k] : b0[k];
    }
}

__global__ __launch_bounds__(TPB) void deform_kernel(
    const float* __restrict__ xd,
    const float* __restrict__ tfs,
    const float* __restrict__ W1, const float* __restrict__ b1,
    const float* __restrict__ W2, const float* __restrict__ b2,
    const float* __restrict__ ws,
    float* __restrict__ out)
{
    // Per-thread LDS columns, phase-overlapped (lanes stride-1 -> conflict-free):
    //   init/Jacobian phase: slots 0..23 = softmax weights w
    //   Broyden phase:       slots 0..8 = Ji, 9 = gno, 10..12 = dx, 13..15 = tx
    __shared__ float stash[24 * TPB];

    const int tid = threadIdx.x;
    const int p   = blockIdx.x * TPB + tid;
    const bool live = (p < NPT);
    const int pc = live ? p : 0;
    const int n  = pc / 9;
    const int c  = pc - n * 9;

    float tx0 = xd[n*3+0], tx1 = xd[n*3+1], tx2 = xd[n*3+2];

    const float* Ti  = ws + WS_TINV + c * 16;
    const float* W0T = ws + WS_W0T;

    float x0 = fmaf(Ti[0], tx0, fmaf(Ti[1], tx1, fmaf(Ti[2],  tx2, Ti[3])));
    float x1 = fmaf(Ti[4], tx0, fmaf(Ti[5], tx1, fmaf(Ti[6],  tx2, Ti[7])));
    float x2 = fmaf(Ti[8], tx0, fmaf(Ti[9], tx1, fmaf(Ti[10], tx2, Ti[11])));

    f2 wr[12];   // layer-3 accumulators -> softmax weights (static-indexed only)

    // forward: fused MLP, z1 as ONE 64-wide register chunk (layer-1 computed once)
    // -> softmax(20*m) -> LBS blend. Leaves w in wr[12]. (round-13 structure)
    auto forward = [&](float a0, float a1, float a2, float& o0, float& o1, float& o2) {
        const f2* b2v = (const f2*)b2;
        #pragma unroll
        for (int q = 0; q < 12; ++q) wr[q] = b2v[q];
        f2 z1[32];
        const f2* b1v = (const f2*)b1;
        #pragma unroll
        for (int j = 0; j < 32; ++j) z1[j] = b1v[j];
        #pragma unroll 2
        for (int k = 0; k < 64; ++k) {
            float w0a = W0T[k*4+0], w0b = W0T[k*4+1], w0c = W0T[k*4+2], w0d = W0T[k*4+3];
            float z  = fmaf(a0, w0a, fmaf(a1, w0b, fmaf(a2, w0c, w0d)));
            float hk = fmaxf(z, 0.f) + __logf(1.f + __expf(-fabsf(z)));
            f2 hk2 = hk;   // broadcast
            const f2* Wr2 = (const f2*)(W1 + k*64);
            #pragma unroll
            for (int j = 0; j < 32; ++j) z1[j] = pk_fma(hk2, Wr2[j], z1[j]);
        }
        #pragma unroll
        for (int j = 0; j < 32; ++j) {
            float za = z1[j].x, zb = z1[j].y;
            float ha = fmaxf(za, 0.f) + __logf(1.f + __expf(-fabsf(za)));
            float hb = fmaxf(zb, 0.f) + __logf(1.f + __expf(-fabsf(zb)));
            const f2* Wa = (const f2*)(W2 + (2*j  )*24);
            const f2* Wb = (const f2*)(W2 + (2*j+1)*24);
            f2 ha2 = ha, hb2 = hb;
            #pragma unroll
            for (int q = 0; q < 12; ++q) wr[q] = pk_fma(ha2, Wa[q], wr[q]);
            #pragma unroll
            for (int q = 0; q < 12; ++q) wr[q] = pk_fma(hb2, Wb[q], wr[q]);
        }
        // softmax(SOFTB * m) — pairwise tree max
        f2 m0 = __builtin_elementwise_max(wr[0], wr[1]);
        f2 m1 = __builtin_elementwise_max(wr[2], wr[3]);
        f2 m2 = __builtin_elementwise_max(wr[4], wr[5]);
        f2 m3 = __builtin_elementwise_max(wr[6], wr[7]);
        f2 m4 = __builtin_elementwise_max(wr[8], wr[9]);
        f2 m5 = __builtin_elementwise_max(wr[10], wr[11]);
        m0 = __builtin_elementwise_max(m0, m1);
        m2 = __builtin_elementwise_max(m2, m3);
        m4 = __builtin_elementwise_max(m4, m5);
        m0 = __builtin_elementwise_max(m0, m2);
        m0 = __builtin_elementwise_max(m0, m4);
        float mx = fmaxf(m0.x, m0.y);
        float ssum = 0.f;
        #pragma unroll
        for (int q = 0; q < 12; ++q) {
            float ea = __expf(SOFTB*(wr[q].x - mx));
            float eb = __expf(SOFTB*(wr[q].y - mx));
            wr[q].x = ea; wr[q].y = eb;
            ssum += ea; ssum += eb;
        }
        float inv = 1.0f / ssum;      // precise: in the exact-trajectory path
        o0 = 0.f; o1 = 0.f; o2 = 0.f;
        #pragma unroll
        for (int q = 0; q < 24; ++q) {
            float wq = ((q & 1) ? wr[q>>1].y : wr[q>>1].x) * inv;
            if (q & 1) wr[q>>1].y = wq; else wr[q>>1].x = wq;
            const float* Tn = tfs + q*16;
            float y0 = fmaf(Tn[0], a0, fmaf(Tn[1], a1, fmaf(Tn[2],  a2, Tn[3])));
            float y1 = fmaf(Tn[4], a0, fmaf(Tn[5], a1, fmaf(Tn[6],  a2, Tn[7])));
            float y2 = fmaf(Tn[8], a0, fmaf(Tn[9], a1, fmaf(Tn[10], a2, Tn[11])));
            o0 = fmaf(wq, y0, o0); o1 = fmaf(wq, y1, o1); o2 = fmaf(wq, y2, o2);
        }
    };

    // ---- init forward (leaves w in wr) ----
    float f0, f1, f2s;
    forward(x0, x1, x2, f0, f1, f2s);

    // persist w to LDS for the Jacobian
    #pragma unroll
    for (int q = 0; q < 24; ++q)
        stash[q*TPB + tid] = (q & 1) ? wr[q>>1].y : wr[q>>1].x;

    // ---- Jacobian: 3 per-tangent JVP passes, 16-wide chunks (round-13 shape,
    // sigmoids via fast rcp — Jacobian-only; empirically validated in round 10) ----
    float Jm[9];   // runtime-t indexed -> scratch; cold
    #pragma unroll 1
    for (int t = 0; t < 3; ++t) {
        float dot = 0.f, sA = 0.f, sB = 0.f, sC = 0.f;
        #pragma unroll 1
        for (int cc = 0; cc < 4; ++cc) {
            f2 z1c[8], d1c[8];
            const f2* b1c = (const f2*)(b1 + cc*16);
            #pragma unroll
            for (int j = 0; j < 8; ++j) { z1c[j] = b1c[j]; d1c[j] = (f2)0.f; }
            #pragma unroll 2
            for (int k = 0; k < 64; ++k) {
                float w0a = W0T[k*4+0], w0b = W0T[k*4+1], w0c = W0T[k*4+2], w0d = W0T[k*4+3];
                float wt  = W0T[k*4 + t];
                float z  = fmaf(x0, w0a, fmaf(x1, w0b, fmaf(x2, w0c, w0d)));
                float e  = __expf(-z);
                float hk = z + __logf(1.f + e);              // softplus(z) (shared e)
                float sg = __builtin_amdgcn_rcpf(1.f + e);   // sigma(z), fast rcp
                float dh0 = sg * wt;
                f2 hk2 = hk, dh02 = dh0;
                const f2* Wr2 = (const f2*)(W1 + k*64 + cc*16);
                #pragma unroll
                for (int j = 0; j < 8; ++j) {
                    z1c[j] = pk_fma(hk2,  Wr2[j], z1c[j]);
                    d1c[j] = pk_fma(dh02, Wr2[j], d1c[j]);
                }
            }
            f2 dmc[12];
            #pragma unroll
            for (int q = 0; q < 12; ++q) dmc[q] = (f2)0.f;
            #pragma unroll
            for (int j = 0; j < 16; ++j) {
                float zz = (j & 1) ? z1c[j>>1].y : z1c[j>>1].x;
                float dd = (j & 1) ? d1c[j>>1].y : d1c[j>>1].x;
                float sg1 = __builtin_amdgcn_rcpf(1.f + __expf(-zz));  // sigma(z1), fast rcp
                float dh1 = dd * sg1;
                f2 dh12 = dh1;
                const f2* W2r = (const f2*)(W2 + (cc*16 + j)*24);
                #pragma unroll
                for (int q = 0; q < 12; ++q) dmc[q] = pk_fma(dh12, W2r[q], dmc[q]);
            }
            #pragma unroll
            for (int q = 0; q < 24; ++q) {
                float dmq = (q & 1) ? dmc[q>>1].y : dmc[q>>1].x;
                float wd = stash[q*TPB + tid] * dmq;           // w from LDS
                dot += wd;
                const float* Tn = tfs + q*16;
                float y0 = fmaf(Tn[0], x0, fmaf(Tn[1], x1, fmaf(Tn[2],  x2, Tn[3])));
                float y1 = fmaf(Tn[4], x0, fmaf(Tn[5], x1, fmaf(Tn[6],  x2, Tn[7])));
                float y2 = fmaf(Tn[8], x0, fmaf(Tn[9], x1, fmaf(Tn[10], x2, Tn[11])));
                sA = fmaf(wd, y0, sA); sB = fmaf(wd, y1, sB); sC = fmaf(wd, y2, sC);
            }
        }
        float ab0 = 0.f, ab1 = 0.f, ab2 = 0.f;
        #pragma unroll
        for (int q = 0; q < 24; ++q) {
            float wq = stash[q*TPB + tid];                     // w from LDS
            const float* Tn = tfs + q*16;
            ab0 = fmaf(wq, Tn[0 + t], ab0);
            ab1 = fmaf(wq, Tn[4 + t], ab1);
            ab2 = fmaf(wq, Tn[8 + t], ab2);
        }
        Jm[0 + t] = ab0 + SOFTB*(sA - dot*f0);
        Jm[3 + t] = ab1 + SOFTB*(sB - dot*f1);
        Jm[6 + t] = ab2 + SOFTB*(sC - dot*f2s);
    }

    // J_inv_init = inv(J) (adjugate) -> Ji into LDS (w slots now dead)
    {
        float m00=Jm[0], m01=Jm[1], m02=Jm[2];
        float m10=Jm[3], m11=Jm[4], m12=Jm[5];
        float m20=Jm[6], m21=Jm[7], m22=Jm[8];
        float c00 = m11*m22 - m12*m21, c01 = m12*m20 - m10*m22, c02 = m10*m21 - m11*m20;
        float det = m00*c00 + m01*c01 + m02*c02;
        float idet = 1.0f / det;
        stash[ 0*TPB+tid] = c00*idet;
        stash[ 1*TPB+tid] = (m02*m21-m01*m22)*idet;
        stash[ 2*TPB+tid] = (m01*m12-m02*m11)*idet;
        stash[ 3*TPB+tid] = c01*idet;
        stash[ 4*TPB+tid] = (m00*m22-m02*m20)*idet;
        stash[ 5*TPB+tid] = (m02*m10-m00*m12)*idet;
        stash[ 6*TPB+tid] = c02*idet;
        stash[ 7*TPB+tid] = (m01*m20-m00*m21)*idet;
        stash[ 8*TPB+tid] = (m00*m11-m01*m10)*idet;
    }
    // tx -> LDS (dead in registers afterwards)
    stash[13*TPB+tid] = tx0;
    stash[14*TPB+tid] = tx1;
    stash[15*TPB+tid] = tx2;

    // ---- Broyden (Ji/gno/dx/tx live in LDS across each forward) ----
    float g0 = f0 - tx0, g1 = f1 - tx1, g2 = f2s - tx2;
    float u0, u1, u2;
    {
        float Ji0=stash[0*TPB+tid], Ji1=stash[1*TPB+tid], Ji2=stash[2*TPB+tid];
        float Ji3=stash[3*TPB+tid], Ji4=stash[4*TPB+tid], Ji5=stash[5*TPB+tid];
        float Ji6=stash[6*TPB+tid], Ji7=stash[7*TPB+tid], Ji8=stash[8*TPB+tid];
        stash[9*TPB+tid] = sqrtf(g0*g0 + g1*g1 + g2*g2);   // gno
        u0 = -(Ji0*g0 + Ji1*g1 + Ji2*g2);
        u1 = -(Ji3*g0 + Ji4*g1 + Ji5*g2);
        u2 = -(Ji6*g0 + Ji7*g1 + Ji8*g2);
    }
    bool valid = true;

    for (int it = 0; it < 20; ++it) {
        if (!__any((int)valid)) break;
        if (valid) {
            // dx -> stash; x += dx
            stash[10*TPB+tid] = u0;
            stash[11*TPB+tid] = u1;
            stash[12*TPB+tid] = u2;
            x0 += u0; x1 += u1; x2 += u2;
            float fn0, fn1, fn2;
            forward(x0, x1, x2, fn0, fn1, fn2);
            float ng0 = fn0 - stash[13*TPB+tid];
            float ng1 = fn1 - stash[14*TPB+tid];
            float ng2 = fn2 - stash[15*TPB+tid];
            float dg0 = ng0 - g0, dg1 = ng1 - g1, dg2 = ng2 - g2;
            g0 = ng0; g1 = ng1; g2 = ng2;
            float gn  = sqrtf(g0*g0 + g1*g1 + g2*g2);
            float gno = fminf(gn, stash[9*TPB+tid]);   // NaN keeps old (matches where)
            stash[9*TPB+tid] = gno;
            valid = (gno > CVGT) && (gn < DVGT);       // NaN -> false (matches)
            if (valid) {
                float Ji0=stash[0*TPB+tid], Ji1=stash[1*TPB+tid], Ji2=stash[2*TPB+tid];
                float Ji3=stash[3*TPB+tid], Ji4=stash[4*TPB+tid], Ji5=stash[5*TPB+tid];
                float Ji6=stash[6*TPB+tid], Ji7=stash[7*TPB+tid], Ji8=stash[8*TPB+tid];
                float dx0=stash[10*TPB+tid], dx1=stash[11*TPB+tid], dx2=stash[12*TPB+tid];
                float v0 = dx0*Ji0 + dx1*Ji3 + dx2*Ji6;
                float v1 = dx0*Ji1 + dx1*Ji4 + dx2*Ji7;
                float v2 = dx0*Ji2 + dx1*Ji5 + dx2*Ji8;
                float a0 = dx0 - (Ji0*dg0 + Ji1*dg1 + Ji2*dg2);
                float a1 = dx1 - (Ji3*dg0 + Ji4*dg1 + Ji5*dg2);
                float a2 = dx2 - (Ji6*dg0 + Ji7*dg1 + Ji8*dg2);
                float b = v0*dg0 + v1*dg1 + v2*dg2;
                b += (b >= 0.f) ? EPSB : -EPSB;
                float ib = 1.0f / b;
                a0 *= ib; a1 *= ib; a2 *= ib;
                Ji0 = fmaf(a0, v0, Ji0); Ji1 = fmaf(a0, v1, Ji1); Ji2 = fmaf(a0, v2, Ji2);
                Ji3 = fmaf(a1, v0, Ji3); Ji4 = fmaf(a1, v1, Ji4); Ji5 = fmaf(a1, v2, Ji5);
                Ji6 = fmaf(a2, v0, Ji6); Ji7 = fmaf(a2, v1, Ji7); Ji8 = fmaf(a2, v2, Ji8);
                stash[0*TPB+tid]=Ji0; stash[1*TPB+tid]=Ji1; stash[2*TPB+tid]=Ji2;
                stash[3*TPB+tid]=Ji3; stash[4*TPB+tid]=Ji4; stash[5*TPB+tid]=Ji5;
                stash[6*TPB+tid]=Ji6; stash[7*TPB+tid]=Ji7; stash[8*TPB+tid]=Ji8;
                u0 = -(Ji0*g0 + Ji1*g1 + Ji2*g2);
                u1 = -(Ji3*g0 + Ji4*g1 + Ji5*g2);
                u2 = -(Ji6*g0 + Ji7*g1 + Ji8*g2);
            }
        }
    }

    if (live) {
        out[p*3+0] = x0;
        out[p*3+1] = x1;
        out[p*3+2] = x2;
    }
}

extern "C" void kernel_launch(void* const* d_in, const int* in_sizes, int n_in,
                              void* d_out, int out_size, void* d_ws, size_t ws_size,
                              hipStream_t stream) {
    const float* xd  = (const float*)d_in[0];
    const float* tfs = (const float*)d_in[1];
    const float* W0  = (const float*)d_in[2];
    const float* b0  = (const float*)d_in[3];
    const float* W1  = (const float*)d_in[4];
    const float* b1  = (const float*)d_in[5];
    const float* W2  = (const float*)d_in[6];
    const float* b2  = (const float*)d_in[7];
    float* out = (float*)d_out;
    float* ws  = (float*)d_ws;

    prep_kernel<<<1, 256, 0, stream>>>(tfs, W0, b0, ws);
    int nblk = (NPT + TPB - 1) / TPB;
    deform_kernel<<<nblk, TPB, 0, stream>>>(xd, tfs, W1, b1, W2, b2, ws, out);
}